// Round 8
// baseline (249.991 us; speedup 1.0000x reference)
//
#include <hip/hip_runtime.h>
#include <hip/hip_bf16.h>
#include <stdint.h>

// CRF nllh = sum_b (logZ_b - score_b).
// logZ via chunked parallel scan in probability domain:
//   alpha_t = alpha_{t-1} * Q_t,  Q_t[i][j] = exp(trans[i][j]/w_{t-1} + em_t[j])
// 64 chunks of 32 steps: chunk computes X_c = (Q_{t0}..Q_{t1-1})^T with
// 32x32x16 bf16 MFMA pairs (X <- Q^T X, K=32 via C-chaining).
// k-permutation sigma folded into A-side constants => D reg-pairs ARE the next
// B operands verbatim (zero cross-lane exchange per step).
// Q entries built as bf16 BITS via magic-constant Schraudolph:
//   f = fma(tpre, 1/w, em*KSC + SBIAS + 2^23); bf16bits = low16(bits(f))
// ILP=2: each wave runs TWO independent chains (batches b, b+1; shared tpre).
// wt/mask hoisted to one load per chunk (lane<->step, readlane broadcast +
// ballot bitmask); em rows loaded split-half (lanes 0-31 row t, lanes 32-63
// row t+1) with depth-2 prefetch. Rescale every 8 steps (log2 offset).
// Gold-path score: lanes 0-31 cover chain0 steps, lanes 32-63 chain1 steps.

#define T_DIM 2048
#define B_DIM 256
#define M_DIM 32
#define CHUNKS 64
#define CLEN 32
#define KSC 184.6649652337873f      /* 128 / ln2 */
#define SBIAS2 12599160.66f         /* 2^23 + 127*128 - 7.34 (log-mean center) */

typedef __attribute__((ext_vector_type(8))) short short8;
typedef __attribute__((ext_vector_type(16))) float f32x16;

__device__ __forceinline__ int pack_bf16(float lo, float hi) {
  union { float f; uint32_t u; } a, b;
  a.f = lo; b.f = hi;
  // result = bf16(lo) | bf16(hi)<<16 (truncation rounding)
  return (int)__builtin_amdgcn_perm(b.u, a.u, 0x07060302u);
}

__device__ __forceinline__ int pack_lo16(int lo, int hi) {
  // (lo & 0xffff) | (hi << 16)
  return (int)__builtin_amdgcn_perm((uint32_t)hi, (uint32_t)lo, 0x05040100u);
}

// ---------------- chunk matrix products (MFMA) + score epilogue ----------------
// 256 threads = 4 waves; each wave handles units 2w and 2w+1 (= chunk c,
// batches b0=2k, b1=2k+1).
__global__ __launch_bounds__(256) void chunk_kernel(
    const float* __restrict__ em, const int* __restrict__ tags,
    const float* __restrict__ wt, const int* __restrict__ mask,
    const float* __restrict__ trans, const float* __restrict__ endt,
    uint32_t* __restrict__ mats, float* __restrict__ offs,
    float* __restrict__ out)
{
  int tid = threadIdx.x;
  int lane = tid & 63;
  int h = lane >> 5;        // wave half
  int r = lane & 31;        // A-row / B-col / D-col index
  int wid = blockIdx.x * 4 + (tid >> 6);
  int unit0 = 2 * wid, unit1 = unit0 + 1;   // same chunk, adjacent batches
  int b0 = unit0 & (B_DIM - 1), b1 = b0 + 1;
  int c = unit0 >> 8;
  int t0 = 1 + c * CLEN;
  int t1 = t0 + CLEN; if (t1 > T_DIM) t1 = T_DIM;

  // A-side transition constants with the k-permutation sigma folded in:
  // sigma1(8h+j) = (j<4 ? j : j+4) + 4h ; sigma2 = sigma1 + 16  (shared by both chains)
  float tpre[16];
#pragma unroll
  for (int j = 0; j < 8; ++j) {
    int row = ((j < 4) ? j : j + 4) + 4 * h;
    tpre[j]     = trans[row * 32 + r] * KSC;
    tpre[8 + j] = trans[(row + 16) * 32 + r] * KSC;
  }

  // ---- hoisted per-chunk scalars: lane s <-> step t0+s (s < CLEN used) ----
  int tw = t0 - 1 + lane; if (tw > T_DIM - 2) tw = T_DIM - 2;   // wt[t-1], t<=2047
  float rwv0 = __builtin_amdgcn_rcpf(wt[tw * B_DIM + b0]);
  float rwv1 = __builtin_amdgcn_rcpf(wt[tw * B_DIM + b1]);
  int tmk = t0 + lane; if (tmk > T_DIM - 1) tmk = T_DIM - 1;
  uint64_t mk0 = __ballot(mask[tmk * B_DIM + b0] != 0);
  uint64_t mk1 = __ballot(mask[tmk * B_DIM + b1] != 0);

  // X = identity in 32x32 D/C layout: reg p holds row (p&3)+8*(p>>2)+4h, col r
  f32x16 X0, X1;
#pragma unroll
  for (int p = 0; p < 16; ++p) {
    float v = (((p & 3) + 8 * (p >> 2) + 4 * h) == r) ? 1.f : 0.f;
    X0[p] = v; X1[p] = v;
  }
  f32x16 z;
#pragma unroll
  for (int u = 0; u < 16; ++u) z[u] = 0.f;

  float off0 = 0.f, off1 = 0.f;   // accumulated log2 rescale offsets

  // em rows: half 0 holds row t, half 1 row t+1; depth-2 prefetch
  float emv0 = em[((size_t)((t0 + h) * B_DIM + b0)) * 32 + r];
  float emv1 = em[((size_t)((t0 + h) * B_DIM + b1)) * 32 + r];
  int tpf = t0 + 2 + h; if (tpf > T_DIM - 1) tpf = T_DIM - 1;
  float emp0 = em[((size_t)(tpf * B_DIM + b0)) * 32 + r];
  float emp1 = em[((size_t)(tpf * B_DIM + b1)) * 32 + r];

  auto step = [&](f32x16& X, float e_em, float rw) {
    float e = fmaf(e_em, KSC, SBIAS2);
    // Q^T A-fragments: magic-fma leaves bf16 bits in low16 of the float
    float qf[16];
#pragma unroll
    for (int j = 0; j < 16; ++j)
      qf[j] = fmaf(tpre[j], rw, e);
    union { int i[4]; short8 s; } af1, af2;
#pragma unroll
    for (int u = 0; u < 4; ++u) {
      af1.i[u] = pack_lo16(__float_as_int(qf[2 * u]),     __float_as_int(qf[2 * u + 1]));
      af2.i[u] = pack_lo16(__float_as_int(qf[8 + 2 * u]), __float_as_int(qf[8 + 2 * u + 1]));
    }
    // B operands = X's D reg-pairs verbatim (sigma absorbed the mismatch)
    union { int i[4]; short8 s; } b1_, b2_;
#pragma unroll
    for (int u = 0; u < 4; ++u) {
      b1_.i[u] = pack_bf16(X[2 * u],     X[2 * u + 1]);
      b2_.i[u] = pack_bf16(X[8 + 2 * u], X[8 + 2 * u + 1]);
    }
    f32x16 d = __builtin_amdgcn_mfma_f32_32x32x16_bf16(af1.s, b1_.s, z, 0, 0, 0);
    X = __builtin_amdgcn_mfma_f32_32x32x16_bf16(af2.s, b2_.s, d, 0, 0, 0);
  };

  auto rescale = [&](f32x16& X, float& off2) {
    float mx = X[0];
#pragma unroll
    for (int u = 1; u < 16; ++u) mx = fmaxf(mx, X[u]);
#pragma unroll
    for (int off = 1; off < 64; off <<= 1) mx = fmaxf(mx, __shfl_xor(mx, off));
    float sc = __builtin_amdgcn_rcpf(mx);
    off2 += __builtin_amdgcn_logf(mx);  // log2
#pragma unroll
    for (int u = 0; u < 16; ++u) X[u] *= sc;
  };

  for (int it = 0; it < CLEN / 2; ++it) {
    // ---- prefetch rows for iteration it+2 (4 steps ahead), clamped ----
    int tn = t0 + 2 * it + 4 + h; if (tn > T_DIM - 1) tn = T_DIM - 1;
    float emn0 = em[((size_t)(tn * B_DIM + b0)) * 32 + r];
    float emn1 = em[((size_t)(tn * B_DIM + b1)) * 32 + r];

    float sw0 = __shfl_xor(emv0, 32);
    float sw1 = __shfl_xor(emv1, 32);

    int sA = 2 * it, sB = sA + 1;
    // step A (t = t0+sA): half 0 holds that row natively
    if ((mk0 >> sA) & 1) step(X0, h ? sw0 : emv0, __shfl(rwv0, sA));
    if ((mk1 >> sA) & 1) step(X1, h ? sw1 : emv1, __shfl(rwv1, sA));
    // step B (t = t0+sB): half 1 holds that row natively
    if (t0 + sB < t1) {
      if ((mk0 >> sB) & 1) step(X0, h ? emv0 : sw0, __shfl(rwv0, sB));
      if ((mk1 >> sB) & 1) step(X1, h ? emv1 : sw1, __shfl(rwv1, sB));
    }

    if ((it & 3) == 3) {  // rescale every 8 steps: keep fp32/bf16 range safe
      rescale(X0, off0);
      rescale(X1, off1);
    }

    emv0 = emp0; emp0 = emn0;
    emv1 = emp1; emp1 = emn1;
  }

  // store X as packed bf16 row-pairs: mp[pair*32 + col] = (X[2p][col], X[2p+1][col])
  uint32_t* mp0 = mats + (size_t)unit0 * 512;
  uint32_t* mp1 = mats + (size_t)unit1 * 512;
#pragma unroll
  for (int u = 0; u < 8; ++u) {
    int pairIdx = (u & 1) + (u >> 1) * 4 + 2 * h;
    mp0[pairIdx * 32 + r] = (uint32_t)pack_bf16(X0[2 * u], X0[2 * u + 1]);
    mp1[pairIdx * 32 + r] = (uint32_t)pack_bf16(X1[2 * u], X1[2 * u + 1]);
  }
  if (lane == 0) { offs[unit0] = off0; offs[unit1] = off1; }

  // ---- score epilogue: lanes 0-31 -> chain0 steps, lanes 32-63 -> chain1 ----
  int bb = h ? b1 : b0;
  int t = t0 + r;
  float ssc = 0.f;
  if (t < t1) {
    int mk  = mask[t * B_DIM + bb];
    int mkn = (t + 1 < T_DIM) ? mask[(t + 1) * B_DIM + bb] : 0;
    int tg  = mk ? tags[t * B_DIM + bb] : 1;
    int mkp = mask[(t - 1) * B_DIM + bb];
    int tgp = mkp ? tags[(t - 1) * B_DIM + bb] : 1;
    if (mk)
      ssc = em[(size_t)(t * B_DIM + bb) * 32 + tg]
          + trans[tgp * 32 + tg] * __builtin_amdgcn_rcpf(wt[(t - 1) * B_DIM + bb]);
    if (mk && !mkn) ssc += endt[tg];
  }
#pragma unroll
  for (int off = 32; off; off >>= 1) ssc += __shfl_xor(ssc, off);
  if (lane == 0) atomicAdd(out, -ssc);
}

// ---------------- combine chunks per batch + t=0 score ----------------
__global__ __launch_bounds__(64) void combine_kernel(
    const float* __restrict__ em, const int* __restrict__ tags,
    const int* __restrict__ mask, const float* __restrict__ startt,
    const float* __restrict__ endt, const uint32_t* __restrict__ mats,
    const float* __restrict__ offs, float* __restrict__ out)
{
  const float INV_LN2 = 1.44269504088896340736f;
  const float LN2 = 0.69314718055994530942f;
  int lane = threadIdx.x;
  int j = lane & 31;          // row handled by this lane (both halves hold av_j)
  int h = lane >> 5;          // which 16-column half this lane accumulates
  int b = blockIdx.x;
  int jp = j >> 1, jh = j & 1;

  float a0 = (startt[j] + em[(size_t)b * 32 + j]) * INV_LN2;  // log2 domain
  float c0 = a0;
#pragma unroll
  for (int off = 1; off < 32; off <<= 1) c0 = fmaxf(c0, __shfl_xor(c0, off));
  float av = __builtin_amdgcn_exp2f(a0 - c0);
  float acc = c0;  // accumulated log2 offset

  // depth-1 prefetch of chunk data
  const uint4* xr0 = (const uint4*)(mats + (size_t)b * 512 + jp * 32 + 16 * h);
  uint4 nv0 = xr0[0], nv1 = xr0[1];
  float noff = offs[b];

  for (int c = 0; c < CHUNKS; ++c) {
    uint4 v0 = nv0, v1 = nv1;
    float offc = noff;
    int cn = (c + 1 < CHUNKS) ? c + 1 : c;
    const uint4* xrn = (const uint4*)(mats + (size_t)(cn * B_DIM + b) * 512 + jp * 32 + 16 * h);
    nv0 = xrn[0]; nv1 = xrn[1];
    noff = offs[cn * B_DIM + b];

    float x[8];
    uint32_t u0[4] = {v0.x, v0.y, v0.z, v0.w};
    uint32_t u1[4] = {v1.x, v1.y, v1.z, v1.w};
#pragma unroll
    for (int e = 0; e < 4; ++e) {
      uint32_t bits0 = jh ? (u0[e] & 0xFFFF0000u) : (u0[e] << 16);
      uint32_t bits1 = jh ? (u1[e] & 0xFFFF0000u) : (u1[e] << 16);
      union { uint32_t uu; float f; } cv0, cv1;
      cv0.uu = bits0; cv1.uu = bits1;
      x[e] = cv0.f; x[4 + e] = cv1.f;
    }
    float s0 = 0.f, s1 = 0.f;
#pragma unroll
    for (int i = 0; i < 4; ++i) {
      s0 = fmaf(x[i],     __shfl(av, 16 * h + i),     s0);
      s1 = fmaf(x[4 + i], __shfl(av, 16 * h + 4 + i), s1);
    }
    float an = s0 + s1;
    an += __shfl_xor(an, 32);   // combine the two column-halves
    float mx = an;
#pragma unroll
    for (int off = 1; off < 32; off <<= 1) mx = fmaxf(mx, __shfl_xor(mx, off));
    av = an * __builtin_amdgcn_rcpf(mx);
    acc += __builtin_amdgcn_logf(mx) + offc;
  }

  float sv = av * __builtin_amdgcn_exp2f(endt[j] * INV_LN2);
#pragma unroll
  for (int off = 1; off < 32; off <<= 1) sv += __shfl_xor(sv, off);
  if (lane == 0) {
    float logZ = (acc + __builtin_amdgcn_logf(sv)) * LN2;
    // t=0 gold-path score terms
    int mk0 = mask[b];
    int tg0 = mk0 ? tags[b] : 1;
    float s0 = startt[tg0] + (mk0 ? em[(size_t)b * 32 + tg0] : 0.f);
    int mk1 = mask[B_DIM + b];
    if (mk0 && !mk1) s0 += endt[tg0];
    atomicAdd(out, logZ - s0);
  }
}

extern "C" void kernel_launch(void* const* d_in, const int* in_sizes, int n_in,
                              void* d_out, int out_size, void* d_ws, size_t ws_size,
                              hipStream_t stream) {
  const float* em   = (const float*)d_in[0];
  const int*   tags = (const int*)d_in[1];
  const float* wt   = (const float*)d_in[2];
  const int*   mask = (const int*)d_in[3];
  const float* tr   = (const float*)d_in[4];
  const float* stt  = (const float*)d_in[5];
  const float* ent  = (const float*)d_in[6];
  float* out = (float*)d_out;

  float* offs = (float*)d_ws;                          // CHUNKS*B floats (64 KB)
  uint32_t* mats = (uint32_t*)(offs + CHUNKS * B_DIM); // CHUNKS*B*512 u32 (~33.6 MB)

  hipMemsetAsync(out, 0, sizeof(float) * out_size, stream);
  chunk_kernel<<<(CHUNKS * B_DIM) / 8, 256, 0, stream>>>(em, tags, wt, mask, tr, ent, mats, offs, out);
  combine_kernel<<<B_DIM, 64, 0, stream>>>(em, tags, mask, stt, ent, mats, offs, out);
}

// Round 9
// 202.068 us; speedup vs baseline: 1.2372x; 1.2372x over previous
//
#include <hip/hip_runtime.h>
#include <hip/hip_bf16.h>
#include <stdint.h>

// CRF nllh = sum_b (logZ_b - score_b).
// logZ via chunked parallel scan in probability domain:
//   alpha_t = alpha_{t-1} * Q_t,  Q_t[i][j] = exp(trans[i][j]/w_{t-1} + em_t[j])
// 32 chunks of 64 steps (R6 config): chunk computes X_c = (Q_{t0}..Q_{t1-1})^T
// with 32x32x16 bf16 MFMA pairs (X <- Q^T X, K=32 via C-chaining).
// k-permutation sigma folded into A-side constants => D reg-pairs ARE the next
// B operands verbatim (zero cross-lane exchange per step).
// Q entries built as bf16 BITS via magic-constant Schraudolph:
//   f = fma(tpre, 1/w, em*KSC + SBIAS + 2^23); bf16bits = low16(bits(f))
// ILP=2: each wave runs TWO independent chains (batches b, b+1; shared tpre).
// FAST PATH (all mask bits set, full 64-step chunk): branch-free inner loop in
// groups of 8 steps -- no per-step conditionals, so the compiler can hoist
// X-independent A-fragment builds across steps/chains and pipeline the
// pack->MFMA->MFMA chains. Masked/short chunks use the general guarded loop.
// Gold-path score = lane-per-timestep epilogue in same kernel.

#define T_DIM 2048
#define B_DIM 256
#define M_DIM 32
#define CHUNKS 32
#define CLEN 64
#define KSC 184.6649652337873f      /* 128 / ln2 */
#define SBIAS2 12599160.66f         /* 2^23 + 127*128 - 7.34 (log-mean center) */

typedef __attribute__((ext_vector_type(8))) short short8;
typedef __attribute__((ext_vector_type(16))) float f32x16;

__device__ __forceinline__ int pack_bf16(float lo, float hi) {
  union { float f; uint32_t u; } a, b;
  a.f = lo; b.f = hi;
  // result = bf16(lo) | bf16(hi)<<16 (truncation rounding)
  return (int)__builtin_amdgcn_perm(b.u, a.u, 0x07060302u);
}

__device__ __forceinline__ int pack_lo16(int lo, int hi) {
  // (lo & 0xffff) | (hi << 16)
  return (int)__builtin_amdgcn_perm((uint32_t)hi, (uint32_t)lo, 0x05040100u);
}

// ---------------- chunk matrix products (MFMA) + score epilogue ----------------
// 256 threads = 4 waves; each wave handles units 2w and 2w+1 (= chunk c,
// batches b0=2k, b1=2k+1).
__global__ __launch_bounds__(256) void chunk_kernel(
    const float* __restrict__ em, const int* __restrict__ tags,
    const float* __restrict__ wt, const int* __restrict__ mask,
    const float* __restrict__ trans, const float* __restrict__ endt,
    uint32_t* __restrict__ mats, float* __restrict__ offs,
    float* __restrict__ out)
{
  int tid = threadIdx.x;
  int lane = tid & 63;
  int h = lane >> 5;        // wave half
  int r = lane & 31;        // A-row / B-col / D-col index
  int wid = blockIdx.x * 4 + (tid >> 6);
  int unit0 = 2 * wid, unit1 = unit0 + 1;   // same chunk, adjacent batches
  int b0 = unit0 & (B_DIM - 1), b1 = b0 + 1;
  int c = unit0 >> 8;
  int t0 = 1 + c * CLEN;
  int t1 = t0 + CLEN; if (t1 > T_DIM) t1 = T_DIM;

  // A-side transition constants with the k-permutation sigma folded in:
  // sigma1(8h+j) = (j<4 ? j : j+4) + 4h ; sigma2 = sigma1 + 16  (shared chains)
  float tpre[16];
#pragma unroll
  for (int j = 0; j < 8; ++j) {
    int row = ((j < 4) ? j : j + 4) + 4 * h;
    tpre[j]     = trans[row * 32 + r] * KSC;
    tpre[8 + j] = trans[(row + 16) * 32 + r] * KSC;
  }

  // ---- hoisted per-chunk scalars: lane s <-> step t0+s ----
  int tw = t0 - 1 + lane; if (tw > T_DIM - 2) tw = T_DIM - 2;
  float rwv0 = __builtin_amdgcn_rcpf(wt[tw * B_DIM + b0]);
  float rwv1 = __builtin_amdgcn_rcpf(wt[tw * B_DIM + b1]);
  int tmk = t0 + lane; if (tmk > T_DIM - 1) tmk = T_DIM - 1;
  uint64_t mk0 = __ballot(mask[tmk * B_DIM + b0] != 0);
  uint64_t mk1 = __ballot(mask[tmk * B_DIM + b1] != 0);
  // mask off phantom bits beyond chunk end
  uint64_t valid = (t1 - t0 >= 64) ? ~0ull : ((1ull << (t1 - t0)) - 1ull);
  mk0 &= valid; mk1 &= valid;

  // X = identity in 32x32 D/C layout: reg p holds row (p&3)+8*(p>>2)+4h, col r
  f32x16 X0, X1;
#pragma unroll
  for (int p = 0; p < 16; ++p) {
    float v = (((p & 3) + 8 * (p >> 2) + 4 * h) == r) ? 1.f : 0.f;
    X0[p] = v; X1[p] = v;
  }
  f32x16 z;
#pragma unroll
  for (int u = 0; u < 16; ++u) z[u] = 0.f;

  float off0 = 0.f, off1 = 0.f;   // accumulated log2 rescale offsets

  auto step = [&](f32x16& X, float e_em, float rw) {
    float e = fmaf(e_em, KSC, SBIAS2);
    // Q^T A-fragments: magic-fma leaves bf16 bits in low16 of the float
    float qf[16];
#pragma unroll
    for (int j = 0; j < 16; ++j)
      qf[j] = fmaf(tpre[j], rw, e);
    union { int i[4]; short8 s; } af1, af2;
#pragma unroll
    for (int u = 0; u < 4; ++u) {
      af1.i[u] = pack_lo16(__float_as_int(qf[2 * u]),     __float_as_int(qf[2 * u + 1]));
      af2.i[u] = pack_lo16(__float_as_int(qf[8 + 2 * u]), __float_as_int(qf[8 + 2 * u + 1]));
    }
    // B operands = X's D reg-pairs verbatim (sigma absorbed the mismatch)
    union { int i[4]; short8 s; } b1_, b2_;
#pragma unroll
    for (int u = 0; u < 4; ++u) {
      b1_.i[u] = pack_bf16(X[2 * u],     X[2 * u + 1]);
      b2_.i[u] = pack_bf16(X[8 + 2 * u], X[8 + 2 * u + 1]);
    }
    f32x16 d = __builtin_amdgcn_mfma_f32_32x32x16_bf16(af1.s, b1_.s, z, 0, 0, 0);
    X = __builtin_amdgcn_mfma_f32_32x32x16_bf16(af2.s, b2_.s, d, 0, 0, 0);
  };

  auto rescale = [&](f32x16& X, float& off2) {
    float mx = X[0];
#pragma unroll
    for (int u = 1; u < 16; ++u) mx = fmaxf(mx, X[u]);
#pragma unroll
    for (int off = 1; off < 64; off <<= 1) mx = fmaxf(mx, __shfl_xor(mx, off));
    float sc = __builtin_amdgcn_rcpf(mx);
    off2 += __builtin_amdgcn_logf(mx);  // log2
#pragma unroll
    for (int u = 0; u < 16; ++u) X[u] *= sc;
  };

  if ((mk0 == ~0ull) && (mk1 == ~0ull)) {
    // ================= FAST PATH: branch-free, groups of 8 steps ============
    float e0[4], e1[4];
#pragma unroll
    for (int u = 0; u < 4; ++u) {
      e0[u] = em[((size_t)((t0 + 2 * u + h) * B_DIM + b0)) * 32 + r];
      e1[u] = em[((size_t)((t0 + 2 * u + h) * B_DIM + b1)) * 32 + r];
    }
    for (int g = 0; g < 8; ++g) {
      // prefetch next group's 8 rows per chain (clamped; last group wasted)
      float n0[4], n1[4];
      int tg = t0 + 8 * (g + 1);
#pragma unroll
      for (int u = 0; u < 4; ++u) {
        int tt = tg + 2 * u + h; if (tt > T_DIM - 1) tt = T_DIM - 1;
        n0[u] = em[((size_t)(tt * B_DIM + b0)) * 32 + r];
        n1[u] = em[((size_t)(tt * B_DIM + b1)) * 32 + r];
      }
#pragma unroll
      for (int u = 0; u < 4; ++u) {
        float sw0 = __shfl_xor(e0[u], 32);
        float sw1 = __shfl_xor(e1[u], 32);
        int sA = 8 * g + 2 * u, sB = sA + 1;
        step(X0, h ? sw0 : e0[u], __shfl(rwv0, sA));
        step(X1, h ? sw1 : e1[u], __shfl(rwv1, sA));
        step(X0, h ? e0[u] : sw0, __shfl(rwv0, sB));
        step(X1, h ? e1[u] : sw1, __shfl(rwv1, sB));
      }
      rescale(X0, off0);
      rescale(X1, off1);
#pragma unroll
      for (int u = 0; u < 4; ++u) { e0[u] = n0[u]; e1[u] = n1[u]; }
    }
  } else {
    // ================= GENERAL PATH: per-step mask guards ===================
    float emv0 = em[((size_t)((t0 + h) * B_DIM + b0)) * 32 + r];
    float emv1 = em[((size_t)((t0 + h) * B_DIM + b1)) * 32 + r];
    int tpf = t0 + 2 + h; if (tpf > T_DIM - 1) tpf = T_DIM - 1;
    float emp0 = em[((size_t)(tpf * B_DIM + b0)) * 32 + r];
    float emp1 = em[((size_t)(tpf * B_DIM + b1)) * 32 + r];

    for (int it = 0; it < CLEN / 2; ++it) {
      int tn = t0 + 2 * it + 4 + h; if (tn > T_DIM - 1) tn = T_DIM - 1;
      float emn0 = em[((size_t)(tn * B_DIM + b0)) * 32 + r];
      float emn1 = em[((size_t)(tn * B_DIM + b1)) * 32 + r];

      float sw0 = __shfl_xor(emv0, 32);
      float sw1 = __shfl_xor(emv1, 32);

      int sA = 2 * it, sB = sA + 1;
      if ((mk0 >> sA) & 1) step(X0, h ? sw0 : emv0, __shfl(rwv0, sA));
      if ((mk1 >> sA) & 1) step(X1, h ? sw1 : emv1, __shfl(rwv1, sA));
      if (t0 + sB < t1) {
        if ((mk0 >> sB) & 1) step(X0, h ? emv0 : sw0, __shfl(rwv0, sB));
        if ((mk1 >> sB) & 1) step(X1, h ? emv1 : sw1, __shfl(rwv1, sB));
      }

      if ((it & 3) == 3) {
        rescale(X0, off0);
        rescale(X1, off1);
      }

      emv0 = emp0; emp0 = emn0;
      emv1 = emp1; emp1 = emn1;
    }
  }

  // store X as packed bf16 row-pairs: mp[pair*32 + col] = (X[2p][col], X[2p+1][col])
  uint32_t* mp0 = mats + (size_t)unit0 * 512;
  uint32_t* mp1 = mats + (size_t)unit1 * 512;
#pragma unroll
  for (int u = 0; u < 8; ++u) {
    int pairIdx = (u & 1) + (u >> 1) * 4 + 2 * h;
    mp0[pairIdx * 32 + r] = (uint32_t)pack_bf16(X0[2 * u], X0[2 * u + 1]);
    mp1[pairIdx * 32 + r] = (uint32_t)pack_bf16(X1[2 * u], X1[2 * u + 1]);
  }
  if (lane == 0) { offs[unit0] = off0; offs[unit1] = off1; }

  // ---- score epilogue: one lane per timestep, both chains ----
  int t = t0 + lane;
  float ssc = 0.f;
  if (t < T_DIM && t < t1) {
    // chain 0
    int mk  = mask[t * B_DIM + b0];
    int mkn = (t + 1 < T_DIM) ? mask[(t + 1) * B_DIM + b0] : 0;
    int tg  = mk ? tags[t * B_DIM + b0] : 1;
    int mkp = mask[(t - 1) * B_DIM + b0];
    int tgp = mkp ? tags[(t - 1) * B_DIM + b0] : 1;
    if (mk)
      ssc = em[(size_t)(t * B_DIM + b0) * 32 + tg]
          + trans[tgp * 32 + tg] * __builtin_amdgcn_rcpf(wt[(t - 1) * B_DIM + b0]);
    if (mk && !mkn) ssc += endt[tg];
    // chain 1
    mk  = mask[t * B_DIM + b1];
    mkn = (t + 1 < T_DIM) ? mask[(t + 1) * B_DIM + b1] : 0;
    tg  = mk ? tags[t * B_DIM + b1] : 1;
    mkp = mask[(t - 1) * B_DIM + b1];
    tgp = mkp ? tags[(t - 1) * B_DIM + b1] : 1;
    if (mk)
      ssc += em[(size_t)(t * B_DIM + b1) * 32 + tg]
           + trans[tgp * 32 + tg] * __builtin_amdgcn_rcpf(wt[(t - 1) * B_DIM + b1]);
    if (mk && !mkn) ssc += endt[tg];
  }
#pragma unroll
  for (int off = 32; off; off >>= 1) ssc += __shfl_xor(ssc, off);
  if (lane == 0) atomicAdd(out, -ssc);
}

// ---------------- combine chunks per batch + t=0 score ----------------
__global__ __launch_bounds__(64) void combine_kernel(
    const float* __restrict__ em, const int* __restrict__ tags,
    const int* __restrict__ mask, const float* __restrict__ startt,
    const float* __restrict__ endt, const uint32_t* __restrict__ mats,
    const float* __restrict__ offs, float* __restrict__ out)
{
  const float INV_LN2 = 1.44269504088896340736f;
  const float LN2 = 0.69314718055994530942f;
  int lane = threadIdx.x;
  int j = lane & 31;          // row handled by this lane (both halves hold av_j)
  int h = lane >> 5;          // which 16-column half this lane accumulates
  int b = blockIdx.x;
  int jp = j >> 1, jh = j & 1;

  float a0 = (startt[j] + em[(size_t)b * 32 + j]) * INV_LN2;  // log2 domain
  float c0 = a0;
#pragma unroll
  for (int off = 1; off < 32; off <<= 1) c0 = fmaxf(c0, __shfl_xor(c0, off));
  float av = __builtin_amdgcn_exp2f(a0 - c0);
  float acc = c0;  // accumulated log2 offset

  // depth-1 prefetch of chunk data
  const uint4* xr0 = (const uint4*)(mats + (size_t)b * 512 + jp * 32 + 16 * h);
  uint4 nv0 = xr0[0], nv1 = xr0[1];
  float noff = offs[b];

  for (int c = 0; c < CHUNKS; ++c) {
    uint4 v0 = nv0, v1 = nv1;
    float offc = noff;
    int cn = (c + 1 < CHUNKS) ? c + 1 : c;
    const uint4* xrn = (const uint4*)(mats + (size_t)(cn * B_DIM + b) * 512 + jp * 32 + 16 * h);
    nv0 = xrn[0]; nv1 = xrn[1];
    noff = offs[cn * B_DIM + b];

    float x[8];
    uint32_t u0[4] = {v0.x, v0.y, v0.z, v0.w};
    uint32_t u1[4] = {v1.x, v1.y, v1.z, v1.w};
#pragma unroll
    for (int e = 0; e < 4; ++e) {
      uint32_t bits0 = jh ? (u0[e] & 0xFFFF0000u) : (u0[e] << 16);
      uint32_t bits1 = jh ? (u1[e] & 0xFFFF0000u) : (u1[e] << 16);
      union { uint32_t uu; float f; } cv0, cv1;
      cv0.uu = bits0; cv1.uu = bits1;
      x[e] = cv0.f; x[4 + e] = cv1.f;
    }
    float s0 = 0.f, s1 = 0.f;
#pragma unroll
    for (int i = 0; i < 4; ++i) {
      s0 = fmaf(x[i],     __shfl(av, 16 * h + i),     s0);
      s1 = fmaf(x[4 + i], __shfl(av, 16 * h + 4 + i), s1);
    }
    float an = s0 + s1;
    an += __shfl_xor(an, 32);   // combine the two column-halves
    float mx = an;
#pragma unroll
    for (int off = 1; off < 32; off <<= 1) mx = fmaxf(mx, __shfl_xor(mx, off));
    av = an * __builtin_amdgcn_rcpf(mx);
    acc += __builtin_amdgcn_logf(mx) + offc;
  }

  float sv = av * __builtin_amdgcn_exp2f(endt[j] * INV_LN2);
#pragma unroll
  for (int off = 1; off < 32; off <<= 1) sv += __shfl_xor(sv, off);
  if (lane == 0) {
    float logZ = (acc + __builtin_amdgcn_logf(sv)) * LN2;
    // t=0 gold-path score terms
    int mk0 = mask[b];
    int tg0 = mk0 ? tags[b] : 1;
    float s0 = startt[tg0] + (mk0 ? em[(size_t)b * 32 + tg0] : 0.f);
    int mk1 = mask[B_DIM + b];
    if (mk0 && !mk1) s0 += endt[tg0];
    atomicAdd(out, logZ - s0);
  }
}

extern "C" void kernel_launch(void* const* d_in, const int* in_sizes, int n_in,
                              void* d_out, int out_size, void* d_ws, size_t ws_size,
                              hipStream_t stream) {
  const float* em   = (const float*)d_in[0];
  const int*   tags = (const int*)d_in[1];
  const float* wt   = (const float*)d_in[2];
  const int*   mask = (const int*)d_in[3];
  const float* tr   = (const float*)d_in[4];
  const float* stt  = (const float*)d_in[5];
  const float* ent  = (const float*)d_in[6];
  float* out = (float*)d_out;

  float* offs = (float*)d_ws;                          // CHUNKS*B floats (32 KB)
  uint32_t* mats = (uint32_t*)(offs + CHUNKS * B_DIM); // CHUNKS*B*512 u32 (~16.8 MB)

  hipMemsetAsync(out, 0, sizeof(float) * out_size, stream);
  chunk_kernel<<<(CHUNKS * B_DIM) / 8, 256, 0, stream>>>(em, tags, wt, mask, tr, ent, mats, offs, out);
  combine_kernel<<<B_DIM, 64, 0, stream>>>(em, tags, mask, stt, ent, mats, offs, out);
}

// Round 10
// 190.586 us; speedup vs baseline: 1.3117x; 1.0602x over previous
//
#include <hip/hip_runtime.h>
#include <hip/hip_bf16.h>
#include <stdint.h>

// CRF nllh = sum_b (logZ_b - score_b).
// logZ via chunked parallel scan in probability domain:
//   alpha_t = alpha_{t-1} * Q_t,  Q_t[i][j] = exp(trans[i][j]/w_{t-1} + em_t[j])
// 32 chunks of 64 steps: chunk computes X_c = (Q_{t0}..Q_{t1-1})^T with
// 32x32x16 bf16 MFMA pairs (X <- Q^T X, K=32 via C-chaining).
// k-permutation sigma folded into A-side constants => D reg-pairs ARE the next
// B operands verbatim (zero cross-lane exchange per step).
// Q entries built as bf16 BITS via magic-constant Schraudolph:
//   f = fma(tpre, 1/w, em*KSC + SBIAS + 2^23); bf16bits = low16(bits(f))
// ILP=4: each wave runs FOUR independent chains (batches b..b+3, shared tpre)
// so the serial pack->MFMA->MFMA latency of one chain is filled by the other
// three -- in-wave ILP beat cross-wave TLP (R6 vs R7 evidence).
// rw broadcast via v_readlane (wave-uniform index -> SGPR operand in the fma)
// instead of ds_bpermute. wt/mask hoisted to one load per chunk; em rows
// loaded split-half (lanes 0-31 row t, lanes 32-63 row t+1), group-of-8-steps
// prefetch. Rescale every 8 steps (log2 offset tracked).
// Gold-path score = lane-per-timestep epilogue in same kernel.

#define T_DIM 2048
#define B_DIM 256
#define M_DIM 32
#define CHUNKS 32
#define CLEN 64
#define KSC 184.6649652337873f      /* 128 / ln2 */
#define SBIAS2 12599160.66f         /* 2^23 + 127*128 - 7.34 (log-mean center) */

typedef __attribute__((ext_vector_type(8))) short short8;
typedef __attribute__((ext_vector_type(16))) float f32x16;

__device__ __forceinline__ int pack_bf16(float lo, float hi) {
  union { float f; uint32_t u; } a, b;
  a.f = lo; b.f = hi;
  // result = bf16(lo) | bf16(hi)<<16 (truncation rounding)
  return (int)__builtin_amdgcn_perm(b.u, a.u, 0x07060302u);
}

__device__ __forceinline__ int pack_lo16(int lo, int hi) {
  // (lo & 0xffff) | (hi << 16)
  return (int)__builtin_amdgcn_perm((uint32_t)hi, (uint32_t)lo, 0x05040100u);
}

__device__ __forceinline__ float bcast_lane(float v, int idx) {
  // wave-uniform broadcast: v_readlane -> SGPR (folds as scalar operand)
  return __int_as_float(__builtin_amdgcn_readlane(__float_as_int(v), idx));
}

// ---------------- chunk matrix products (MFMA) + score epilogue ----------------
// 256 threads = 4 waves; each wave handles units 4w..4w+3 (= chunk c,
// batches bb..bb+3).
__global__ __launch_bounds__(256) void chunk_kernel(
    const float* __restrict__ em, const int* __restrict__ tags,
    const float* __restrict__ wt, const int* __restrict__ mask,
    const float* __restrict__ trans, const float* __restrict__ endt,
    uint32_t* __restrict__ mats, float* __restrict__ offs,
    float* __restrict__ out)
{
  int tid = threadIdx.x;
  int lane = tid & 63;
  int h = lane >> 5;        // wave half
  int r = lane & 31;        // A-row / B-col / D-col index
  int wid = blockIdx.x * 4 + (tid >> 6);
  int u0 = 4 * wid;                      // first unit = c*B + bb
  int bb = u0 & (B_DIM - 1);             // base batch (multiple of 4)
  int c = u0 >> 8;
  int t0 = 1 + c * CLEN;
  int t1 = t0 + CLEN; if (t1 > T_DIM) t1 = T_DIM;

  // A-side transition constants with the k-permutation sigma folded in:
  // sigma1(8h+j) = (j<4 ? j : j+4) + 4h ; sigma2 = sigma1 + 16  (shared chains)
  float tpre[16];
#pragma unroll
  for (int j = 0; j < 8; ++j) {
    int row = ((j < 4) ? j : j + 4) + 4 * h;
    tpre[j]     = trans[row * 32 + r] * KSC;
    tpre[8 + j] = trans[(row + 16) * 32 + r] * KSC;
  }

  // ---- hoisted per-chunk scalars: lane s <-> step t0+s ----
  int tw = t0 - 1 + lane; if (tw > T_DIM - 1) tw = T_DIM - 1;
  int tmk = t0 + lane; if (tmk > T_DIM - 1) tmk = T_DIM - 1;
  float rwv[4];
  uint64_t mk[4];
  uint64_t valid = (t1 - t0 >= 64) ? ~0ull : ((1ull << (t1 - t0)) - 1ull);
#pragma unroll
  for (int ch = 0; ch < 4; ++ch) {
    rwv[ch] = __builtin_amdgcn_rcpf(wt[tw * B_DIM + bb + ch]);
    mk[ch] = __ballot(mask[tmk * B_DIM + bb + ch] != 0) & valid;
  }

  // X = identity in 32x32 D/C layout: reg p holds row (p&3)+8*(p>>2)+4h, col r
  f32x16 X[4];
#pragma unroll
  for (int p = 0; p < 16; ++p) {
    float v = (((p & 3) + 8 * (p >> 2) + 4 * h) == r) ? 1.f : 0.f;
    X[0][p] = v; X[1][p] = v; X[2][p] = v; X[3][p] = v;
  }
  f32x16 z;
#pragma unroll
  for (int u = 0; u < 16; ++u) z[u] = 0.f;

  float off2[4] = {0.f, 0.f, 0.f, 0.f};

  auto step = [&](f32x16& Xc, float e_em, float rw) {
    float e = fmaf(e_em, KSC, SBIAS2);
    // Q^T A-fragments: magic-fma leaves bf16 bits in low16 of the float
    float qf[16];
#pragma unroll
    for (int j = 0; j < 16; ++j)
      qf[j] = fmaf(tpre[j], rw, e);
    union { int i[4]; short8 s; } af1, af2;
#pragma unroll
    for (int u = 0; u < 4; ++u) {
      af1.i[u] = pack_lo16(__float_as_int(qf[2 * u]),     __float_as_int(qf[2 * u + 1]));
      af2.i[u] = pack_lo16(__float_as_int(qf[8 + 2 * u]), __float_as_int(qf[8 + 2 * u + 1]));
    }
    // B operands = X's D reg-pairs verbatim (sigma absorbed the mismatch)
    union { int i[4]; short8 s; } b1_, b2_;
#pragma unroll
    for (int u = 0; u < 4; ++u) {
      b1_.i[u] = pack_bf16(Xc[2 * u],     Xc[2 * u + 1]);
      b2_.i[u] = pack_bf16(Xc[8 + 2 * u], Xc[8 + 2 * u + 1]);
    }
    f32x16 d = __builtin_amdgcn_mfma_f32_32x32x16_bf16(af1.s, b1_.s, z, 0, 0, 0);
    Xc = __builtin_amdgcn_mfma_f32_32x32x16_bf16(af2.s, b2_.s, d, 0, 0, 0);
  };

  auto rescale = [&](f32x16& Xc, float& o2) {
    float mx = Xc[0];
#pragma unroll
    for (int u = 1; u < 16; ++u) mx = fmaxf(mx, Xc[u]);
#pragma unroll
    for (int off = 1; off < 64; off <<= 1) mx = fmaxf(mx, __shfl_xor(mx, off));
    float sc = __builtin_amdgcn_rcpf(mx);
    o2 += __builtin_amdgcn_logf(mx);  // log2
#pragma unroll
    for (int u = 0; u < 16; ++u) Xc[u] *= sc;
  };

  bool fast = (t1 - t0 == 64) && (mk[0] == ~0ull) && (mk[1] == ~0ull)
            && (mk[2] == ~0ull) && (mk[3] == ~0ull);

  if (fast) {
    // ================= FAST PATH: branch-free, groups of 8 steps ============
    float e[4][4], n[4][4];
#pragma unroll
    for (int ch = 0; ch < 4; ++ch)
#pragma unroll
      for (int u = 0; u < 4; ++u)
        e[ch][u] = em[((size_t)((t0 + 2 * u + h) * B_DIM + bb + ch)) * 32 + r];
    for (int g = 0; g < 8; ++g) {
      int tg = t0 + 8 * (g + 1);
#pragma unroll
      for (int ch = 0; ch < 4; ++ch)
#pragma unroll
        for (int u = 0; u < 4; ++u) {
          int tt = tg + 2 * u + h; if (tt > T_DIM - 1) tt = T_DIM - 1;
          n[ch][u] = em[((size_t)(tt * B_DIM + bb + ch)) * 32 + r];
        }
#pragma unroll
      for (int u = 0; u < 4; ++u) {
        int sA = 8 * g + 2 * u, sB = sA + 1;
        float sw[4];
#pragma unroll
        for (int ch = 0; ch < 4; ++ch) sw[ch] = __shfl_xor(e[ch][u], 32);
#pragma unroll
        for (int ch = 0; ch < 4; ++ch)
          step(X[ch], h ? sw[ch] : e[ch][u], bcast_lane(rwv[ch], sA));
#pragma unroll
        for (int ch = 0; ch < 4; ++ch)
          step(X[ch], h ? e[ch][u] : sw[ch], bcast_lane(rwv[ch], sB));
      }
#pragma unroll
      for (int ch = 0; ch < 4; ++ch) rescale(X[ch], off2[ch]);
#pragma unroll
      for (int ch = 0; ch < 4; ++ch)
#pragma unroll
        for (int u = 0; u < 4; ++u) e[ch][u] = n[ch][u];
    }
  } else {
    // ================= GENERAL PATH: per-step mask guards ===================
    float emv[4], emp[4];
#pragma unroll
    for (int ch = 0; ch < 4; ++ch)
      emv[ch] = em[((size_t)((t0 + h) * B_DIM + bb + ch)) * 32 + r];
    int tpf = t0 + 2 + h; if (tpf > T_DIM - 1) tpf = T_DIM - 1;
#pragma unroll
    for (int ch = 0; ch < 4; ++ch)
      emp[ch] = em[((size_t)(tpf * B_DIM + bb + ch)) * 32 + r];

    for (int it = 0; it < CLEN / 2; ++it) {
      int tn = t0 + 2 * it + 4 + h; if (tn > T_DIM - 1) tn = T_DIM - 1;
      float emn[4];
#pragma unroll
      for (int ch = 0; ch < 4; ++ch)
        emn[ch] = em[((size_t)(tn * B_DIM + bb + ch)) * 32 + r];

      int sA = 2 * it, sB = sA + 1;
#pragma unroll
      for (int ch = 0; ch < 4; ++ch) {
        float sw = __shfl_xor(emv[ch], 32);
        if ((mk[ch] >> sA) & 1)
          step(X[ch], h ? sw : emv[ch], bcast_lane(rwv[ch], sA));
        if ((t0 + sB < t1) && ((mk[ch] >> sB) & 1))
          step(X[ch], h ? emv[ch] : sw, bcast_lane(rwv[ch], sB));
      }

      if ((it & 3) == 3) {
#pragma unroll
        for (int ch = 0; ch < 4; ++ch) rescale(X[ch], off2[ch]);
      }
#pragma unroll
      for (int ch = 0; ch < 4; ++ch) { emv[ch] = emp[ch]; emp[ch] = emn[ch]; }
    }
  }

  // store X as packed bf16 row-pairs: mp[pair*32 + col] = (X[2p][col], X[2p+1][col])
#pragma unroll
  for (int ch = 0; ch < 4; ++ch) {
    uint32_t* mp = mats + (size_t)(u0 + ch) * 512;
#pragma unroll
    for (int u = 0; u < 8; ++u) {
      int pairIdx = (u & 1) + (u >> 1) * 4 + 2 * h;
      mp[pairIdx * 32 + r] = (uint32_t)pack_bf16(X[ch][2 * u], X[ch][2 * u + 1]);
    }
  }
  if (lane == 0) {
#pragma unroll
    for (int ch = 0; ch < 4; ++ch) offs[u0 + ch] = off2[ch];
  }

  // ---- score epilogue: one lane per timestep, all 4 chains ----
  int t = t0 + lane;
  float ssc = 0.f;
  if (t < t1) {
#pragma unroll
    for (int ch = 0; ch < 4; ++ch) {
      int b = bb + ch;
      int mkc  = mask[t * B_DIM + b];
      int mkn  = (t + 1 < T_DIM) ? mask[(t + 1) * B_DIM + b] : 0;
      int tg   = mkc ? tags[t * B_DIM + b] : 1;
      int mkp  = mask[(t - 1) * B_DIM + b];
      int tgp  = mkp ? tags[(t - 1) * B_DIM + b] : 1;
      if (mkc)
        ssc += em[(size_t)(t * B_DIM + b) * 32 + tg]
             + trans[tgp * 32 + tg] * __builtin_amdgcn_rcpf(wt[(t - 1) * B_DIM + b]);
      if (mkc && !mkn) ssc += endt[tg];
    }
  }
#pragma unroll
  for (int off = 32; off; off >>= 1) ssc += __shfl_xor(ssc, off);
  if (lane == 0) atomicAdd(out, -ssc);
}

// ---------------- combine chunks per batch + t=0 score ----------------
__global__ __launch_bounds__(64) void combine_kernel(
    const float* __restrict__ em, const int* __restrict__ tags,
    const int* __restrict__ mask, const float* __restrict__ startt,
    const float* __restrict__ endt, const uint32_t* __restrict__ mats,
    const float* __restrict__ offs, float* __restrict__ out)
{
  const float INV_LN2 = 1.44269504088896340736f;
  const float LN2 = 0.69314718055994530942f;
  int lane = threadIdx.x;
  int j = lane & 31;          // row handled by this lane (both halves hold av_j)
  int h = lane >> 5;          // which 16-column half this lane accumulates
  int b = blockIdx.x;
  int jp = j >> 1, jh = j & 1;

  float a0 = (startt[j] + em[(size_t)b * 32 + j]) * INV_LN2;  // log2 domain
  float c0 = a0;
#pragma unroll
  for (int off = 1; off < 32; off <<= 1) c0 = fmaxf(c0, __shfl_xor(c0, off));
  float av = __builtin_amdgcn_exp2f(a0 - c0);
  float acc = c0;  // accumulated log2 offset

  // depth-1 prefetch of chunk data
  const uint4* xr0 = (const uint4*)(mats + (size_t)b * 512 + jp * 32 + 16 * h);
  uint4 nv0 = xr0[0], nv1 = xr0[1];
  float noff = offs[b];

  for (int c = 0; c < CHUNKS; ++c) {
    uint4 v0 = nv0, v1 = nv1;
    float offc = noff;
    int cn = (c + 1 < CHUNKS) ? c + 1 : c;
    const uint4* xrn = (const uint4*)(mats + (size_t)(cn * B_DIM + b) * 512 + jp * 32 + 16 * h);
    nv0 = xrn[0]; nv1 = xrn[1];
    noff = offs[cn * B_DIM + b];

    float x[8];
    uint32_t u0[4] = {v0.x, v0.y, v0.z, v0.w};
    uint32_t u1[4] = {v1.x, v1.y, v1.z, v1.w};
#pragma unroll
    for (int e = 0; e < 4; ++e) {
      uint32_t bits0 = jh ? (u0[e] & 0xFFFF0000u) : (u0[e] << 16);
      uint32_t bits1 = jh ? (u1[e] & 0xFFFF0000u) : (u1[e] << 16);
      union { uint32_t uu; float f; } cv0, cv1;
      cv0.uu = bits0; cv1.uu = bits1;
      x[e] = cv0.f; x[4 + e] = cv1.f;
    }
    float s0 = 0.f, s1 = 0.f;
#pragma unroll
    for (int i = 0; i < 4; ++i) {
      s0 = fmaf(x[i],     __shfl(av, 16 * h + i),     s0);
      s1 = fmaf(x[4 + i], __shfl(av, 16 * h + 4 + i), s1);
    }
    float an = s0 + s1;
    an += __shfl_xor(an, 32);   // combine the two column-halves
    float mx = an;
#pragma unroll
    for (int off = 1; off < 32; off <<= 1) mx = fmaxf(mx, __shfl_xor(mx, off));
    av = an * __builtin_amdgcn_rcpf(mx);
    acc += __builtin_amdgcn_logf(mx) + offc;
  }

  float sv = av * __builtin_amdgcn_exp2f(endt[j] * INV_LN2);
#pragma unroll
  for (int off = 1; off < 32; off <<= 1) sv += __shfl_xor(sv, off);
  if (lane == 0) {
    float logZ = (acc + __builtin_amdgcn_logf(sv)) * LN2;
    // t=0 gold-path score terms
    int mk0 = mask[b];
    int tg0 = mk0 ? tags[b] : 1;
    float s0 = startt[tg0] + (mk0 ? em[(size_t)b * 32 + tg0] : 0.f);
    int mk1 = mask[B_DIM + b];
    if (mk0 && !mk1) s0 += endt[tg0];
    atomicAdd(out, logZ - s0);
  }
}

extern "C" void kernel_launch(void* const* d_in, const int* in_sizes, int n_in,
                              void* d_out, int out_size, void* d_ws, size_t ws_size,
                              hipStream_t stream) {
  const float* em   = (const float*)d_in[0];
  const int*   tags = (const int*)d_in[1];
  const float* wt   = (const float*)d_in[2];
  const int*   mask = (const int*)d_in[3];
  const float* tr   = (const float*)d_in[4];
  const float* stt  = (const float*)d_in[5];
  const float* ent  = (const float*)d_in[6];
  float* out = (float*)d_out;

  float* offs = (float*)d_ws;                          // CHUNKS*B floats (32 KB)
  uint32_t* mats = (uint32_t*)(offs + CHUNKS * B_DIM); // CHUNKS*B*512 u32 (~16.8 MB)

  hipMemsetAsync(out, 0, sizeof(float) * out_size, stream);
  chunk_kernel<<<(CHUNKS * B_DIM) / 16, 256, 0, stream>>>(em, tags, wt, mask, tr, ent, mats, offs, out);
  combine_kernel<<<B_DIM, 64, 0, stream>>>(em, tags, mask, stt, ent, mats, offs, out);
}